// Round 8
// baseline (137.496 us; speedup 1.0000x reference)
//
#include <hip/hip_runtime.h>
#include <stdint.h>

#define BATCH 32
#define H 512
#define W 512
#define NACC 16
#define TH 32              // center rows per tile
#define HALO 9             // need M_1..M_9 only
#define RH (TH + 2*HALO)   // 50 rows incl. halo
#define NT 1024
#define NW (NT/64)         // 16 waves
#define NTILE (H/TH)       // 16
#define NBLK (NTILE*BATCH) // 512 blocks = 2/CU (full 32-wave occupancy)

// part[fid*NACC + k] per-block partials (no atomics, deterministic):
//  0: sum(p*g)  1: sum(p)  2: sum(g)
//  3: cnt_pe 4: cnt_pm 5: cnt_pj  6: cnt_ge 7: cnt_gm 8: cnt_gj
//  9: int_e 10: int_m 11: int_j
// 12: dsum_p2g 13: cnt_p2g 14: dsum_g2p 15: cnt_g2p

__global__ __launch_bounds__(NT, 8) void fused_kernel(
    const float* __restrict__ pred, const float* __restrict__ gt,
    float* __restrict__ part)
{
    __shared__ uint64_t Mp[2][RH][8];    // pred mask, double-buffered
    __shared__ uint64_t Mg[2][RH][8];    // gt mask
    __shared__ float    EC[2][TH];       // pred colsums at cols 255|256
    __shared__ float    red[NW][16];

    // XCD swizzle: vertically-adjacent tiles land on the same XCD (mod-8
    // round-robin dispatch) so shared halo rows hit that XCD's L2.
    int fid = blockIdx.x;
    int b   = fid >> 4;
    int t4  = fid & 15;
    int tile = ((t4 & 7) << 1) | (t4 >> 3);

    const float* pimg = pred + (size_t)b * H * W;
    const float* gimg = gt   + (size_t)b * H * W;
    int y0 = tile * TH;
    int tid = threadIdx.x, lane = tid & 63, wid = tid >> 6;

    // ---- Phase 1: ballot masks, rows y0-9..y0+40 (400 word-tasks, x2 unroll,
    // 4 global loads in flight per wave iteration — x4 spilled at the 64-VGPR
    // cap in R7; x2 fits)
    for (int s = wid; s < RH * 8; s += 2 * NW) {
        int sB = s + NW;
        int rA = s >> 3, segA = s & 7;
        int rB = sB >> 3, segB = sB & 7;
        int ryA = y0 - HALO + rA, ryB = y0 - HALO + rB;
        bool okB = sB < RH * 8;
        float vpA = 0.f, vgA = 0.f, vpB = 0.f, vgB = 0.f;
        if ((unsigned)ryA < (unsigned)H) {
            int idx = ryA * W + segA * 64 + lane;
            vpA = pimg[idx]; vgA = gimg[idx];
        }
        if (okB && (unsigned)ryB < (unsigned)H) {
            int idx = ryB * W + segB * 64 + lane;
            vpB = pimg[idx]; vgB = gimg[idx];
        }
        unsigned long long mpA = __ballot(vpA > 0.5f);
        unsigned long long mgA = __ballot(vgA > 0.5f);
        if (lane == 0) { Mp[0][rA][segA] = mpA; Mg[0][rA][segA] = mgA; }
        if (okB) {   // wave-uniform
            unsigned long long mpB = __ballot(vpB > 0.5f);
            unsigned long long mgB = __ballot(vgB > 0.5f);
            if (lane == 0) { Mp[0][rB][segB] = mpB; Mg[0][rB][segB] = mgB; }
        }
    }
    // pred edge colsums (cols 255,256) for the cross-wave stencil halo
    if (tid < 2 * TH) {
        int c = tid >> 5, r = tid & (TH - 1);
        int y = y0 + r, col = 255 + c;
        float sum = (y > 0     ? pimg[(size_t)(y - 1) * W + col] : 0.f)
                  +              pimg[(size_t)y * W + col]
                  + (y < H - 1 ? pimg[(size_t)(y + 1) * W + col] : 0.f);
        EC[c][r] = sum;
    }
    __syncthreads();

    // ---- Target bits for distance (center 32 rows = 256 words, tid<256)
    uint64_t Tp = 0ULL, Tg = 0ULL;
    int rT = HALO + (tid >> 3), wT = tid & 7;
    if (tid < TH * 8) { Tp = Mp[0][rT][wT]; Tg = Mg[0][rT][wT]; }
    int dcnt_p = __popcll(Tp), dcnt_g = __popcll(Tg);
    int dsum_p = dcnt_p, dsum_g = dcnt_g;   // a=0 baseline (dist >= 1)

    // ---- Stencil + dice: pred via floats (rolling rows), gt via bit popcounts
    float v0 = 0.f, v1 = 0.f;
    float c3=0,c4=0,c5=0,c6=0,c7=0,c8=0,c9=0,c10=0,c11=0;
    {
        int qi = tid & 127, h = tid >> 7;     // h in 0..7, 4 rows each
        int x4 = qi * 4;
        int wdx = qi >> 4;                    // word for this quad
        int ss = (qi & 15) * 4;               // bit offset of x4 in word
        int ys = y0 + h * 4;

        auto win6 = [&](int rb) -> uint32_t {
            const uint64_t* row = Mg[0][rb];
            uint64_t bm = row[wdx];
            if (ss == 0) {
                uint64_t lo = wdx ? row[wdx - 1] : 0ULL;
                return (uint32_t)(((bm << 1) | (lo >> 63)) & 0x3FULL);
            }
            uint32_t v = (uint32_t)((bm >> (ss - 1)) & 0x3FULL);
            if (ss == 60) {
                uint64_t hi = (wdx < 7) ? row[wdx + 1] : 0ULL;
                v |= ((uint32_t)hi & 1u) << 5;
            }
            return v;
        };

        int rb0 = h * 4 + HALO - 1;           // bit-row of (ys-1)
        uint32_t wU = win6(rb0), wM = win6(rb0 + 1);

        float4 pm4, pc4;
        {
            bool hm = ys > 0;
            pm4 = hm ? *(const float4*)(pimg + (size_t)(ys - 1) * W + x4)
                     : make_float4(0, 0, 0, 0);
            pc4 = *(const float4*)(pimg + (size_t)ys * W + x4);
        }
        for (int r = 0; r < 4; ++r) {
            int y = ys + r;
            float4 pp4 = (y < H - 1) ? *(const float4*)(pimg + (size_t)(y + 1) * W + x4)
                                     : make_float4(0, 0, 0, 0);
            uint32_t wD = win6(rb0 + 2 + r);
            int ry = h * 4 + r;

            float ps[6];
            ps[1] = pm4.x + pc4.x + pp4.x; ps[2] = pm4.y + pc4.y + pp4.y;
            ps[3] = pm4.z + pc4.z + pp4.z; ps[4] = pm4.w + pc4.w + pp4.w;
            float psl = __shfl_up(ps[4], 1, 64);
            float psr = __shfl_down(ps[1], 1, 64);
            if (lane == 0)  psl = (qi == 0)   ? 0.f : EC[0][ry];
            if (lane == 63) psr = (qi == 127) ? 0.f : EC[1][ry];
            ps[0] = psl; ps[5] = psr;

            float pcv[4] = {pc4.x, pc4.y, pc4.z, pc4.w};
            #pragma unroll
            for (int j = 0; j < 4; ++j) {
                float np = ps[j] + ps[j + 1] + ps[j + 2] - pcv[j];
                bool pon = pcv[j] > 0.5f;
                bool pe  = pon && (np == 1.f);
                bool pmb = pon && (np == 2.f);
                bool pjb = pon && (np > 2.f);
                uint32_t n9 = ((wU >> j) & 7u) | (((wM >> j) & 7u) << 3) | (((wD >> j) & 7u) << 6);
                uint32_t cen = (wM >> (j + 1)) & 1u;
                int ng = __popc(n9) - (int)cen;
                bool gon = cen != 0u;
                bool ge  = gon && (ng == 1);
                bool gmb = gon && (ng == 2);
                bool gjb = gon && (ng > 2);
                v1 += pcv[j];
                v0 += gon ? pcv[j] : 0.f;
                c3 += pe;  c4 += pmb;  c5 += pjb;
                c6 += ge;  c7 += gmb;  c8 += gjb;
                c9  += (pe && ge);
                c10 += (pmb && gmb);
                c11 += (pjb && gjb);
            }
            pm4 = pc4; pc4 = pp4; wU = wM; wM = wD;
        }
    }

    // ---- 9 bit-dilation steps: p/g split across thread halves, shrinking
    // active rows (step a only needs rows [a, RH-1-a]); popcount after each.
    int cur = 0;
    int half = tid >> 9;           // 0: pred mask, 1: gt mask
    int t    = tid & 511;
    for (int a = 1; a <= 9; ++a) {
        int ntask = (RH - 2 * a) * 8;        // 384..256, multiple of 16
        if (t < ntask) {
            int r = a + (t >> 3), w = t & 7;
            uint64_t (*Msrc)[8] = half ? Mg[cur] : Mp[cur];
            uint64_t (*Mdst)[8] = half ? Mg[cur ^ 1] : Mp[cur ^ 1];
            uint64_t X = Msrc[r - 1][w] | Msrc[r][w] | Msrc[r + 1][w];
            uint32_t lm = __shfl_up  ((uint32_t)(X >> 63), 1, 64);
            uint32_t rl = __shfl_down((uint32_t)(X & 1ULL), 1, 64);
            uint64_t Y = X | (X << 1) | (X >> 1);
            if (w > 0) Y |= (uint64_t)(lm & 1u);
            if (w < 7) Y |= ((uint64_t)(rl & 1u)) << 63;
            Mdst[r][w] = Y;
        }
        __syncthreads();
        cur ^= 1;
        if (tid < TH * 8) {
            dsum_p += __popcll(Tp & ~Mg[cur][rT][wT]);  // pred targets vs gt coverage
            dsum_g += __popcll(Tg & ~Mp[cur][rT][wT]);  // gt targets vs pred coverage
        }
    }

    // ---- Reductions -> per-block partials (no atomics)
    float vals[16];
    vals[0] = v0; vals[1] = v1; vals[2] = (float)dcnt_g;
    vals[3] = c3; vals[4] = c4; vals[5] = c5;
    vals[6] = c6; vals[7] = c7; vals[8] = c8;
    vals[9] = c9; vals[10] = c10; vals[11] = c11;
    vals[12] = (float)dsum_p; vals[13] = (float)dcnt_p;
    vals[14] = (float)dsum_g; vals[15] = (float)dcnt_g;
    #pragma unroll
    for (int j = 0; j < 16; ++j)
        #pragma unroll
        for (int off = 32; off; off >>= 1)
            vals[j] += __shfl_down(vals[j], off, 64);
    if (lane == 0) {
        #pragma unroll
        for (int j = 0; j < 16; ++j) red[wid][j] = vals[j];
    }
    __syncthreads();
    if (tid < 16) {
        float s = 0.f;
        #pragma unroll
        for (int wv = 0; wv < NW; ++wv) s += red[wv][tid];
        part[fid * NACC + tid] = s;
    }
}

// ---------------------------------------------------------------------------
// Final: reduce 512x16 partials -> 32x16 -> scalar. One block, deterministic.
// ---------------------------------------------------------------------------
__global__ __launch_bounds__(512) void final_kernel(
    const float* __restrict__ part, float* __restrict__ out)
{
    __shared__ float sacc[BATCH][NACC];
    __shared__ float tri[BATCH][3];
    int t = threadIdx.x;
    {
        int b = t >> 4, k = t & 15;
        float s = 0.f;
        #pragma unroll 4
        for (int j = 0; j < NTILE; ++j)
            s += part[((b << 4) + j) * NACC + k];
        sacc[b][k] = s;
    }
    __syncthreads();
    if (t < BATCH) {
        const float* a = sacc[t];
        float inter = a[0], psum = a[1], gsum = a[2];
        float dice = (2.f * inter + 1.f) / (psum + gsum + 1.f);

        float pe = a[3], pm = a[4], pj = a[5];
        float ge = a[6], gm = a[7], gj = a[8];
        float ie = a[9], im = a[10], ij = a[11];
        float e_iou = (ie + 1.f) / (pe + ge - ie + 1.f);
        float m_iou = (im + 1.f) / (pm + gm - im + 1.f);
        float j_iou = (ij + 1.f) / (pj + gj - ij + 1.f);
        float total = ge + gj + gm + 1.f;
        float sloss = 1.f - ((ge / total) * e_iou + (gj / total) * j_iou + (gm / total) * m_iou);

        float p2g = a[12] / (a[13] + 1.f);
        float g2p = a[14] / (a[15] + 1.f);
        float med = ((p2g + g2p) * 0.5f) / 10.f;
        tri[t][0] = dice; tri[t][1] = sloss; tri[t][2] = med;
    }
    __syncthreads();
    if (t == 0) {
        float dice = 0.f, sloss = 0.f, med = 0.f;
        for (int b = 0; b < BATCH; ++b) {
            dice += tri[b][0]; sloss += tri[b][1]; med += tri[b][2];
        }
        float dice_loss  = 1.f - dice / (float)BATCH;
        float structural = sloss / (float)BATCH;
        float medial     = med / (float)BATCH;
        float avg = (dice_loss + structural + medial) / 3.f;
        float r = dice_loss  / (dice_loss  + 1.f) * avg
                + structural / (structural + 1.f) * avg
                + medial     / (medial     + 1.f) * avg;
        out[0] = r;
    }
}

extern "C" void kernel_launch(void* const* d_in, const int* in_sizes, int n_in,
                              void* d_out, int out_size, void* d_ws, size_t ws_size,
                              hipStream_t stream)
{
    const float* pred = (const float*)d_in[0];
    const float* gt   = (const float*)d_in[1];
    float* part = (float*)d_ws;
    float* out  = (float*)d_out;

    fused_kernel<<<dim3(NBLK), NT, 0, stream>>>(pred, gt, part);
    final_kernel<<<1, 512, 0, stream>>>(part, out);
}

// Round 9
// 124.094 us; speedup vs baseline: 1.1080x; 1.1080x over previous
//
#include <hip/hip_runtime.h>
#include <stdint.h>

#define BATCH 32
#define H 512
#define W 512
#define NACC 16
#define TH 32              // center rows per tile
#define HALO 9             // need M_1..M_9 only
#define RH (TH + 2*HALO)   // 50 rows incl. halo
#define NT 1024
#define NW (NT/64)         // 16 waves
#define NTILE (H/TH)       // 16
#define NBLK (NTILE*BATCH) // 512 blocks

// part[fid*NACC + k] per-block partials (no atomics, deterministic):
//  0: sum(p*g)  1: sum(p)  2: sum(g)
//  3: cnt_pe 4: cnt_pm 5: cnt_pj  6: cnt_ge 7: cnt_gm 8: cnt_gj
//  9: int_e 10: int_m 11: int_j
// 12: dsum_p2g 13: cnt_p2g 14: dsum_g2p 15: cnt_g2p

// NOTE: __launch_bounds__(1024,8) [R7/R8] forced a 64-VGPR budget; backend
// allocated 32 VGPR + ~118 MB of scratch spill traffic (WRITE_SIZE 62 MB).
// (1024,4) lifts the cap to 128 — no spill.
__global__ __launch_bounds__(NT, 4) void fused_kernel(
    const float* __restrict__ pred, const float* __restrict__ gt,
    float* __restrict__ part)
{
    __shared__ uint64_t Mp[2][RH][8];    // pred mask, double-buffered
    __shared__ uint64_t Mg[2][RH][8];    // gt mask
    __shared__ float    EC[2][TH];       // pred colsums at cols 255|256
    __shared__ float    red[NW][16];

    // XCD swizzle: vertically-adjacent tiles land on the same XCD (mod-8
    // round-robin dispatch) so shared halo rows hit that XCD's L2.
    int fid = blockIdx.x;
    int b   = fid >> 4;
    int t4  = fid & 15;
    int tile = ((t4 & 7) << 1) | (t4 >> 3);

    const float* pimg = pred + (size_t)b * H * W;
    const float* gimg = gt   + (size_t)b * H * W;
    int y0 = tile * TH;
    int tid = threadIdx.x, lane = tid & 63, wid = tid >> 6;

    // ---- Phase 1: ballot masks, rows y0-9..y0+40 (400 word-tasks, x2 unroll)
    for (int s = wid; s < RH * 8; s += 2 * NW) {
        int sB = s + NW;
        int rA = s >> 3, segA = s & 7;
        int rB = sB >> 3, segB = sB & 7;
        int ryA = y0 - HALO + rA, ryB = y0 - HALO + rB;
        bool okB = sB < RH * 8;
        float vpA = 0.f, vgA = 0.f, vpB = 0.f, vgB = 0.f;
        if ((unsigned)ryA < (unsigned)H) {
            int idx = ryA * W + segA * 64 + lane;
            vpA = pimg[idx]; vgA = gimg[idx];
        }
        if (okB && (unsigned)ryB < (unsigned)H) {
            int idx = ryB * W + segB * 64 + lane;
            vpB = pimg[idx]; vgB = gimg[idx];
        }
        unsigned long long mpA = __ballot(vpA > 0.5f);
        unsigned long long mgA = __ballot(vgA > 0.5f);
        if (lane == 0) { Mp[0][rA][segA] = mpA; Mg[0][rA][segA] = mgA; }
        if (okB) {   // wave-uniform
            unsigned long long mpB = __ballot(vpB > 0.5f);
            unsigned long long mgB = __ballot(vgB > 0.5f);
            if (lane == 0) { Mp[0][rB][segB] = mpB; Mg[0][rB][segB] = mgB; }
        }
    }
    // pred edge colsums (cols 255,256) for the cross-wave stencil halo
    if (tid < 2 * TH) {
        int c = tid >> 5, r = tid & (TH - 1);
        int y = y0 + r, col = 255 + c;
        float sum = (y > 0     ? pimg[(size_t)(y - 1) * W + col] : 0.f)
                  +              pimg[(size_t)y * W + col]
                  + (y < H - 1 ? pimg[(size_t)(y + 1) * W + col] : 0.f);
        EC[c][r] = sum;
    }
    __syncthreads();

    // ---- Target bits for distance (center 32 rows = 256 words, tid<256)
    uint64_t Tp = 0ULL, Tg = 0ULL;
    int rT = HALO + (tid >> 3), wT = tid & 7;
    if (tid < TH * 8) { Tp = Mp[0][rT][wT]; Tg = Mg[0][rT][wT]; }
    int dcnt_p = __popcll(Tp), dcnt_g = __popcll(Tg);
    int dsum_p = dcnt_p, dsum_g = dcnt_g;   // a=0 baseline (dist >= 1)

    // ---- Stencil + dice: pred via floats (rolling rows), gt via bit popcounts
    // 9 classification counters packed into one u64 (7-bit fields, max 16/thr)
    float v0 = 0.f, v1 = 0.f;
    uint64_t cpack = 0ULL;
    {
        int qi = tid & 127, h = tid >> 7;     // h in 0..7, 4 rows each
        int x4 = qi * 4;
        int wdx = qi >> 4;                    // word for this quad
        int ss = (qi & 15) * 4;               // bit offset of x4 in word
        int ys = y0 + h * 4;

        auto win6 = [&](int rb) -> uint32_t {
            const uint64_t* row = Mg[0][rb];
            uint64_t bm = row[wdx];
            if (ss == 0) {
                uint64_t lo = wdx ? row[wdx - 1] : 0ULL;
                return (uint32_t)(((bm << 1) | (lo >> 63)) & 0x3FULL);
            }
            uint32_t v = (uint32_t)((bm >> (ss - 1)) & 0x3FULL);
            if (ss == 60) {
                uint64_t hi = (wdx < 7) ? row[wdx + 1] : 0ULL;
                v |= ((uint32_t)hi & 1u) << 5;
            }
            return v;
        };

        int rb0 = h * 4 + HALO - 1;           // bit-row of (ys-1)
        uint32_t wU = win6(rb0), wM = win6(rb0 + 1);

        float4 pm4, pc4;
        {
            bool hm = ys > 0;
            pm4 = hm ? *(const float4*)(pimg + (size_t)(ys - 1) * W + x4)
                     : make_float4(0, 0, 0, 0);
            pc4 = *(const float4*)(pimg + (size_t)ys * W + x4);
        }
        for (int r = 0; r < 4; ++r) {
            int y = ys + r;
            float4 pp4 = (y < H - 1) ? *(const float4*)(pimg + (size_t)(y + 1) * W + x4)
                                     : make_float4(0, 0, 0, 0);
            uint32_t wD = win6(rb0 + 2 + r);
            int ry = h * 4 + r;

            float ps[6];
            ps[1] = pm4.x + pc4.x + pp4.x; ps[2] = pm4.y + pc4.y + pp4.y;
            ps[3] = pm4.z + pc4.z + pp4.z; ps[4] = pm4.w + pc4.w + pp4.w;
            float psl = __shfl_up(ps[4], 1, 64);
            float psr = __shfl_down(ps[1], 1, 64);
            if (lane == 0)  psl = (qi == 0)   ? 0.f : EC[0][ry];
            if (lane == 63) psr = (qi == 127) ? 0.f : EC[1][ry];
            ps[0] = psl; ps[5] = psr;

            float pcv[4] = {pc4.x, pc4.y, pc4.z, pc4.w};
            #pragma unroll
            for (int j = 0; j < 4; ++j) {
                float np = ps[j] + ps[j + 1] + ps[j + 2] - pcv[j];
                bool pon = pcv[j] > 0.5f;
                bool pe  = pon && (np == 1.f);
                bool pmb = pon && (np == 2.f);
                bool pjb = pon && (np > 2.f);
                uint32_t n9 = ((wU >> j) & 7u) | (((wM >> j) & 7u) << 3) | (((wD >> j) & 7u) << 6);
                uint32_t cen = (wM >> (j + 1)) & 1u;
                int ng = __popc(n9) - (int)cen;
                bool gon = cen != 0u;
                bool ge  = gon && (ng == 1);
                bool gmb = gon && (ng == 2);
                bool gjb = gon && (ng > 2);
                v1 += pcv[j];
                v0 += gon ? pcv[j] : 0.f;
                cpack += (uint64_t)pe
                       | ((uint64_t)pmb << 7)
                       | ((uint64_t)pjb << 14)
                       | ((uint64_t)ge  << 21)
                       | ((uint64_t)gmb << 28)
                       | ((uint64_t)gjb << 35)
                       | ((uint64_t)(pe  && ge)  << 42)
                       | ((uint64_t)(pmb && gmb) << 49)
                       | ((uint64_t)(pjb && gjb) << 56);
            }
            pm4 = pc4; pc4 = pp4; wU = wM; wM = wD;
        }
    }

    // ---- 9 bit-dilation steps: p/g split across thread halves, shrinking
    // active rows (step a only needs rows [a, RH-1-a]); popcount after each.
    int cur = 0;
    int half = tid >> 9;           // 0: pred mask, 1: gt mask
    int t    = tid & 511;
    for (int a = 1; a <= 9; ++a) {
        int ntask = (RH - 2 * a) * 8;        // 384..256, multiple of 16
        if (t < ntask) {
            int r = a + (t >> 3), w = t & 7;
            uint64_t (*Msrc)[8] = half ? Mg[cur] : Mp[cur];
            uint64_t (*Mdst)[8] = half ? Mg[cur ^ 1] : Mp[cur ^ 1];
            uint64_t X = Msrc[r - 1][w] | Msrc[r][w] | Msrc[r + 1][w];
            uint32_t lm = __shfl_up  ((uint32_t)(X >> 63), 1, 64);
            uint32_t rl = __shfl_down((uint32_t)(X & 1ULL), 1, 64);
            uint64_t Y = X | (X << 1) | (X >> 1);
            if (w > 0) Y |= (uint64_t)(lm & 1u);
            if (w < 7) Y |= ((uint64_t)(rl & 1u)) << 63;
            Mdst[r][w] = Y;
        }
        __syncthreads();
        cur ^= 1;
        if (tid < TH * 8) {
            dsum_p += __popcll(Tp & ~Mg[cur][rT][wT]);  // pred targets vs gt coverage
            dsum_g += __popcll(Tg & ~Mp[cur][rT][wT]);  // gt targets vs pred coverage
        }
    }

    // ---- Reductions -> per-block partials (no atomics)
    float vals[16];
    vals[0] = v0; vals[1] = v1; vals[2] = (float)dcnt_g;
    vals[3]  = (float)((cpack      ) & 0x7F);
    vals[4]  = (float)((cpack >> 7 ) & 0x7F);
    vals[5]  = (float)((cpack >> 14) & 0x7F);
    vals[6]  = (float)((cpack >> 21) & 0x7F);
    vals[7]  = (float)((cpack >> 28) & 0x7F);
    vals[8]  = (float)((cpack >> 35) & 0x7F);
    vals[9]  = (float)((cpack >> 42) & 0x7F);
    vals[10] = (float)((cpack >> 49) & 0x7F);
    vals[11] = (float)((cpack >> 56) & 0x7F);
    vals[12] = (float)dsum_p; vals[13] = (float)dcnt_p;
    vals[14] = (float)dsum_g; vals[15] = (float)dcnt_g;
    #pragma unroll
    for (int j = 0; j < 16; ++j)
        #pragma unroll
        for (int off = 32; off; off >>= 1)
            vals[j] += __shfl_down(vals[j], off, 64);
    if (lane == 0) {
        #pragma unroll
        for (int j = 0; j < 16; ++j) red[wid][j] = vals[j];
    }
    __syncthreads();
    if (tid < 16) {
        float s = 0.f;
        #pragma unroll
        for (int wv = 0; wv < NW; ++wv) s += red[wv][tid];
        part[fid * NACC + tid] = s;
    }
}

// ---------------------------------------------------------------------------
// Final: reduce 512x16 partials -> 32x16 -> scalar. One block, deterministic.
// ---------------------------------------------------------------------------
__global__ __launch_bounds__(512) void final_kernel(
    const float* __restrict__ part, float* __restrict__ out)
{
    __shared__ float sacc[BATCH][NACC];
    __shared__ float tri[BATCH][3];
    int t = threadIdx.x;
    {
        int b = t >> 4, k = t & 15;
        float s = 0.f;
        #pragma unroll 4
        for (int j = 0; j < NTILE; ++j)
            s += part[((b << 4) + j) * NACC + k];
        sacc[b][k] = s;
    }
    __syncthreads();
    if (t < BATCH) {
        const float* a = sacc[t];
        float inter = a[0], psum = a[1], gsum = a[2];
        float dice = (2.f * inter + 1.f) / (psum + gsum + 1.f);

        float pe = a[3], pm = a[4], pj = a[5];
        float ge = a[6], gm = a[7], gj = a[8];
        float ie = a[9], im = a[10], ij = a[11];
        float e_iou = (ie + 1.f) / (pe + ge - ie + 1.f);
        float m_iou = (im + 1.f) / (pm + gm - im + 1.f);
        float j_iou = (ij + 1.f) / (pj + gj - ij + 1.f);
        float total = ge + gj + gm + 1.f;
        float sloss = 1.f - ((ge / total) * e_iou + (gj / total) * j_iou + (gm / total) * m_iou);

        float p2g = a[12] / (a[13] + 1.f);
        float g2p = a[14] / (a[15] + 1.f);
        float med = ((p2g + g2p) * 0.5f) / 10.f;
        tri[t][0] = dice; tri[t][1] = sloss; tri[t][2] = med;
    }
    __syncthreads();
    if (t == 0) {
        float dice = 0.f, sloss = 0.f, med = 0.f;
        for (int b = 0; b < BATCH; ++b) {
            dice += tri[b][0]; sloss += tri[b][1]; med += tri[b][2];
        }
        float dice_loss  = 1.f - dice / (float)BATCH;
        float structural = sloss / (float)BATCH;
        float medial     = med / (float)BATCH;
        float avg = (dice_loss + structural + medial) / 3.f;
        float r = dice_loss  / (dice_loss  + 1.f) * avg
                + structural / (structural + 1.f) * avg
                + medial     / (medial     + 1.f) * avg;
        out[0] = r;
    }
}

extern "C" void kernel_launch(void* const* d_in, const int* in_sizes, int n_in,
                              void* d_out, int out_size, void* d_ws, size_t ws_size,
                              hipStream_t stream)
{
    const float* pred = (const float*)d_in[0];
    const float* gt   = (const float*)d_in[1];
    float* part = (float*)d_ws;
    float* out  = (float*)d_out;

    fused_kernel<<<dim3(NBLK), NT, 0, stream>>>(pred, gt, part);
    final_kernel<<<1, 512, 0, stream>>>(part, out);
}